// Round 19
// baseline (43.123 us; speedup 1.0000x reference)
//
#include <hip/hip_runtime.h>
#include <hip/hip_fp16.h>

#define LOG2E    1.4426950408889634f
#define TWOLOG2E 2.8853900817779268f

// ---------------------------------------------------------------------------
// MEASUREMENT ROUND (pv): R17 pipeline (31.8us best), pv launched 3x; first
// two write DISTINCT scratch outputs (no cross-XCD WAW artifact), last writes
// the real out.  t_pv = (T - 31.8) / 2.
// ---------------------------------------------------------------------------

// Kernel 1: projections -> fp16 exponentials (verbatim R17).
__global__ __launch_bounds__(256) void proj_kernel(
    const float* __restrict__ queries, const float* __restrict__ keys,
    const float* __restrict__ Wq, const float* __restrict__ Wk,
    __half* __restrict__ eq, __half* __restrict__ ek)
{
    __shared__ float xs[8 * 128];
    const int isK = blockIdx.x >= 256;
    const int rowBase = (blockIdx.x & 255) * 8;
    const float* __restrict__ x = isK ? keys : queries;
    const float* __restrict__ W = isK ? Wk : Wq;
    __half* __restrict__ op = isK ? ek : eq;
    const int t = threadIdx.x;

    ((float4*)xs)[t] = ((const float4*)(x + (size_t)rowBase * 128))[t];
    __syncthreads();

    const int h  = t & 127;
    const int rh = t >> 7;
    const float4* wrow = (const float4*)(W + (size_t)h * 128);
    float acc[4] = {0.f, 0.f, 0.f, 0.f};

    #pragma unroll 4
    for (int d4 = 0; d4 < 32; ++d4) {
        float4 w = wrow[d4];
        #pragma unroll
        for (int r = 0; r < 4; ++r) {
            float4 xv = *(const float4*)&xs[(rh * 4 + r) * 128 + d4 * 4];
            acc[r] = fmaf(xv.x, w.x, acc[r]);
            acc[r] = fmaf(xv.y, w.y, acc[r]);
            acc[r] = fmaf(xv.z, w.z, acc[r]);
            acc[r] = fmaf(xv.w, w.w, acc[r]);
        }
    }
    #pragma unroll
    for (int r = 0; r < 4; ++r)
        op[(size_t)(rowBase + rh * 4 + r) * 128 + h] =
            __float2half(__builtin_amdgcn_exp2f(acc[r] * TWOLOG2E));
}

// Kernel 2: scoreP (verbatim R17).
#define LDP 130

__global__ __launch_bounds__(256) void scoreP_kernel(
    const __half* __restrict__ eq, const __half* __restrict__ ek,
    const float* __restrict__ wv, __half* __restrict__ P,
    float* __restrict__ Zpart)
{
    __shared__ float qs[32 * LDP];
    __shared__ float ks_[32 * LDP];
    __shared__ float part2[4][32];

    const int kt = blockIdx.x, qt = blockIdx.y, b = blockIdx.z;
    const int t = threadIdx.x;

    {
        const int r = t >> 3, c = (t & 7) * 16;
        const __half2* qh = (const __half2*)(eq + (size_t)(b * 256 + qt * 32 + r) * 128 + c);
        const __half2* kh = (const __half2*)(ek + (size_t)(b * 256 + kt * 32 + r) * 128 + c);
        #pragma unroll
        for (int j = 0; j < 8; ++j) {
            float2 fq = __half22float2(qh[j]);
            float2 fk = __half22float2(kh[j]);
            *(float2*)&qs[r * LDP + c + 2 * j]  = fq;
            *(float2*)&ks_[r * LDP + c + 2 * j] = fk;
        }
    }
    __syncthreads();

    const int lk = (t & 15) * 2;
    const int lq = (t >> 4) * 2;

    float a00 = 0.f, a01 = 0.f, a10 = 0.f, a11 = 0.f;
    float wsum = 0.f;

    #pragma unroll 4
    for (int h = 0; h < 128; h += 4) {
        float4 w4 = *(const float4*)&wv[h];
        wsum += (w4.x + w4.y) + (w4.z + w4.w);
        float4 qa = *(const float4*)&qs[lq * LDP + h];
        float4 qb = *(const float4*)&qs[(lq + 1) * LDP + h];
        float4 ka = *(const float4*)&ks_[lk * LDP + h];
        float4 kb = *(const float4*)&ks_[(lk + 1) * LDP + h];
        const float wj[4]  = {w4.x, w4.y, w4.z, w4.w};
        const float qaj[4] = {qa.x, qa.y, qa.z, qa.w};
        const float qbj[4] = {qb.x, qb.y, qb.z, qb.w};
        const float kaj[4] = {ka.x, ka.y, ka.z, ka.w};
        const float kbj[4] = {kb.x, kb.y, kb.z, kb.w};
        #pragma unroll
        for (int j = 0; j < 4; ++j) {
            float r00 = __builtin_amdgcn_rcpf(fmaf(qaj[j], kaj[j], 1.0f));
            float r01 = __builtin_amdgcn_rcpf(fmaf(qaj[j], kbj[j], 1.0f));
            float r10 = __builtin_amdgcn_rcpf(fmaf(qbj[j], kaj[j], 1.0f));
            float r11 = __builtin_amdgcn_rcpf(fmaf(qbj[j], kbj[j], 1.0f));
            a00 = fmaf(wj[j], r00, a00);
            a01 = fmaf(wj[j], r01, a01);
            a10 = fmaf(wj[j], r10, a10);
            a11 = fmaf(wj[j], r11, a11);
        }
    }

    const float wsl = fmaf(wsum, LOG2E, -0.5f);
    const float M2L = -2.0f * LOG2E;
    float p00 = __builtin_amdgcn_exp2f(fmaf(M2L, a00, wsl));
    float p01 = __builtin_amdgcn_exp2f(fmaf(M2L, a01, wsl));
    float p10 = __builtin_amdgcn_exp2f(fmaf(M2L, a10, wsl));
    float p11 = __builtin_amdgcn_exp2f(fmaf(M2L, a11, wsl));

    const int q = qt * 32 + lq;
    const int k = kt * 32 + lk;
    *(__half2*)&P[((size_t)(b * 256 + q)) * 256 + k]     = __floats2half2_rn(p00, p01);
    *(__half2*)&P[((size_t)(b * 256 + q + 1)) * 256 + k] = __floats2half2_rn(p10, p11);

    float sa = p00 + p10;
    float sb = p01 + p11;
    sa += __shfl_xor(sa, 16, 64);
    sa += __shfl_xor(sa, 32, 64);
    sb += __shfl_xor(sb, 16, 64);
    sb += __shfl_xor(sb, 32, 64);
    const int wid = t >> 6;
    if ((t & 63) < 16) {
        part2[wid][lk]     = sa;
        part2[wid][lk + 1] = sb;
    }
    __syncthreads();
    if (t < 32) {
        float z = part2[0][t] + part2[1][t] + part2[2][t] + part2[3][t];
        Zpart[(size_t)b * 2048 + qt * 256 + kt * 32 + t] = z;
    }
}

// Kernel 3: pv (verbatim R17).
__global__ __launch_bounds__(256) void pv_kernel(
    const __half* __restrict__ P, const float* __restrict__ Zpart,
    const float* __restrict__ values, float* __restrict__ out)
{
    __shared__ float ps[4 * 260];
    __shared__ float red[4 * 512];
    const int b  = blockIdx.x >> 6;
    const int q0 = (blockIdx.x & 63) * 4;
    const int t  = threadIdx.x;

    {
        const int q = t >> 6;
        const int k = (t & 63) * 4;
        const float* zb = Zpart + (size_t)b * 2048 + k;
        float4 z = make_float4(0.f, 0.f, 0.f, 0.f);
        #pragma unroll
        for (int qt = 0; qt < 8; ++qt) {
            float4 a = *(const float4*)(zb + qt * 256);
            z.x += a.x; z.y += a.y; z.z += a.z; z.w += a.w;
        }
        const __half* prow = P + ((size_t)(b * 256 + q0 + q)) * 256 + k;
        float2 s0 = __half22float2(*(const __half2*)(prow));
        float2 s1 = __half22float2(*(const __half2*)(prow + 2));
        float4 r;
        r.x = s0.x * __builtin_amdgcn_rcpf(z.x);
        r.y = s0.y * __builtin_amdgcn_rcpf(z.y);
        r.z = s1.x * __builtin_amdgcn_rcpf(z.z);
        r.w = s1.y * __builtin_amdgcn_rcpf(z.w);
        *(float4*)&ps[q * 260 + k] = r;
    }
    __syncthreads();

    const int wid  = t >> 6;
    const int lane = t & 63;
    const float* vb = values + (size_t)b * 256 * 128 + lane * 2;

    float ax[4] = {0.f, 0.f, 0.f, 0.f};
    float ay[4] = {0.f, 0.f, 0.f, 0.f};

    for (int kk4 = wid * 16; kk4 < wid * 16 + 16; ++kk4) {
        float4 p0 = *(const float4*)&ps[0 * 260 + kk4 * 4];
        float4 p1 = *(const float4*)&ps[1 * 260 + kk4 * 4];
        float4 p2 = *(const float4*)&ps[2 * 260 + kk4 * 4];
        float4 p3 = *(const float4*)&ps[3 * 260 + kk4 * 4];
        #pragma unroll
        for (int u = 0; u < 4; ++u) {
            int kk = kk4 * 4 + u;
            float2 v = *(const float2*)(vb + (size_t)kk * 128);
            float f0 = (&p0.x)[u], f1 = (&p1.x)[u], f2 = (&p2.x)[u], f3 = (&p3.x)[u];
            ax[0] = fmaf(f0, v.x, ax[0]); ay[0] = fmaf(f0, v.y, ay[0]);
            ax[1] = fmaf(f1, v.x, ax[1]); ay[1] = fmaf(f1, v.y, ay[1]);
            ax[2] = fmaf(f2, v.x, ax[2]); ay[2] = fmaf(f2, v.y, ay[2]);
            ax[3] = fmaf(f3, v.x, ax[3]); ay[3] = fmaf(f3, v.y, ay[3]);
        }
    }

    #pragma unroll
    for (int q = 0; q < 4; ++q)
        *(float2*)&red[wid * 512 + q * 128 + lane * 2] = make_float2(ax[q], ay[q]);
    __syncthreads();

    {
        const int j = t * 2;
        float2 s = make_float2(0.f, 0.f);
        #pragma unroll
        for (int w = 0; w < 4; ++w) {
            float2 r = *(const float2*)&red[w * 512 + j];
            s.x += r.x; s.y += r.y;
        }
        const int q = j >> 7, d = j & 127;
        *(float2*)&out[((size_t)(b * 256 + q0 + q)) * 128 + d] = s;
    }
}

// ---------------------------------------------------------------------------
extern "C" void kernel_launch(void* const* d_in, const int* in_sizes, int n_in,
                              void* d_out, int out_size, void* d_ws, size_t ws_size,
                              hipStream_t stream)
{
    const float* queries = (const float*)d_in[0];  // (8,256,128)
    const float* keys    = (const float*)d_in[1];  // (8,256,128)
    const float* values  = (const float*)d_in[2];  // (8,256,128)
    const float* Wq      = (const float*)d_in[3];  // (128,128)
    const float* Wk      = (const float*)d_in[4];  // (128,128)
    const float* wv      = (const float*)d_in[5];  // (128,)
    float* out = (float*)d_out;                    // (8,256,128)

    float* ws = (float*)d_ws;
    __half* eqb  = (__half*)ws;              // 262144 halves (512KB)
    __half* ekb  = (__half*)(ws + 131072);   // 262144 halves (512KB)
    __half* P    = (__half*)(ws + 262144);   // 524288 halves (1MB)
    float* Zpart = ws + 524288;              // 16384 floats
    float* scr0  = ws + 540672;              // 262144 floats scratch out
    float* scr1  = ws + 802816;              // 262144 floats scratch out

    proj_kernel<<<512, 256, 0, stream>>>(queries, keys, Wq, Wk, eqb, ekb);
    scoreP_kernel<<<dim3(8, 8, 8), 256, 0, stream>>>(eqb, ekb, wv, P, Zpart);
    // AMPLIFY pv x3: t_pv = (T - 31.8us) / 2
    pv_kernel<<<512, 256, 0, stream>>>(P, Zpart, values, scr0);
    pv_kernel<<<512, 256, 0, stream>>>(P, Zpart, values, scr1);
    pv_kernel<<<512, 256, 0, stream>>>(P, Zpart, values, out);
}

// Round 20
// 31.321 us; speedup vs baseline: 1.3768x; 1.3768x over previous
//
#include <hip/hip_runtime.h>
#include <hip/hip_fp16.h>

#define LOG2E    1.4426950408889634f
#define TWOLOG2E 2.8853900817779268f

// ---------------------------------------------------------------------------
// 3-launch pipeline, fp16 intermediates (R17 = 31.8us best).
// proj v3: xs LDS staging DELETED.  The x reads are wave-uniform (rh = t>>7
// constant per wave, d4 loop-uniform), so they go through the SCALAR pipe
// (s_load_dwordx4) instead of 128 ds_read_b128/wave on the LDS pipe -- which
// the pipe accounting shows was proj's 5.1us bound (128*12cyc*8waves/CU).
//   K1 proj   -> eq = fp16(exp(2*q@Wq^T)), ek likewise
//   K2 scoreP -> P = fp16(exp2(score*log2e - 0.5)) + fp32 column partials
//   K3 pv     -> out = (P/Z) @ V
// ---------------------------------------------------------------------------

// Kernel 1: projections -> fp16 exponentials. 512 blocks, 256 thr, 8 rows/blk.
__global__ __launch_bounds__(256) void proj_kernel(
    const float* __restrict__ queries, const float* __restrict__ keys,
    const float* __restrict__ Wq, const float* __restrict__ Wk,
    __half* __restrict__ eq, __half* __restrict__ ek)
{
    const int isK = blockIdx.x >= 256;
    const int rowBase = (blockIdx.x & 255) * 8;
    const float* __restrict__ x = isK ? keys : queries;
    const float* __restrict__ W = isK ? Wk : Wq;
    __half* __restrict__ op = isK ? ek : eq;
    const int t = threadIdx.x;

    const int h   = t & 127;
    const int rhu = __builtin_amdgcn_readfirstlane(t >> 7);  // wave-uniform
    const float4* wrow = (const float4*)(W + (size_t)h * 128);
    // uniform row base pointers -> scalar loads
    const float4* xr0 = (const float4*)(x + (size_t)(rowBase + rhu * 4 + 0) * 128);
    const float4* xr1 = (const float4*)(x + (size_t)(rowBase + rhu * 4 + 1) * 128);
    const float4* xr2 = (const float4*)(x + (size_t)(rowBase + rhu * 4 + 2) * 128);
    const float4* xr3 = (const float4*)(x + (size_t)(rowBase + rhu * 4 + 3) * 128);

    float acc[4] = {0.f, 0.f, 0.f, 0.f};

    #pragma unroll 4
    for (int d4 = 0; d4 < 32; ++d4) {
        float4 w  = wrow[d4];            // per-lane row stream (L1/L2)
        float4 x0 = xr0[d4];             // wave-uniform -> s_load_dwordx4
        float4 x1 = xr1[d4];
        float4 x2 = xr2[d4];
        float4 x3 = xr3[d4];
        acc[0] = fmaf(x0.x, w.x, acc[0]); acc[0] = fmaf(x0.y, w.y, acc[0]);
        acc[0] = fmaf(x0.z, w.z, acc[0]); acc[0] = fmaf(x0.w, w.w, acc[0]);
        acc[1] = fmaf(x1.x, w.x, acc[1]); acc[1] = fmaf(x1.y, w.y, acc[1]);
        acc[1] = fmaf(x1.z, w.z, acc[1]); acc[1] = fmaf(x1.w, w.w, acc[1]);
        acc[2] = fmaf(x2.x, w.x, acc[2]); acc[2] = fmaf(x2.y, w.y, acc[2]);
        acc[2] = fmaf(x2.z, w.z, acc[2]); acc[2] = fmaf(x2.w, w.w, acc[2]);
        acc[3] = fmaf(x3.x, w.x, acc[3]); acc[3] = fmaf(x3.y, w.y, acc[3]);
        acc[3] = fmaf(x3.z, w.z, acc[3]); acc[3] = fmaf(x3.w, w.w, acc[3]);
    }
    #pragma unroll
    for (int r = 0; r < 4; ++r)          // coalesced 2B stores
        op[(size_t)(rowBase + rhu * 4 + r) * 128 + h] =
            __float2half(__builtin_amdgcn_exp2f(acc[r] * TWOLOG2E));
}

// Kernel 2: scoreP (verbatim R17).
#define LDP 130

__global__ __launch_bounds__(256) void scoreP_kernel(
    const __half* __restrict__ eq, const __half* __restrict__ ek,
    const float* __restrict__ wv, __half* __restrict__ P,
    float* __restrict__ Zpart)
{
    __shared__ float qs[32 * LDP];
    __shared__ float ks_[32 * LDP];
    __shared__ float part2[4][32];

    const int kt = blockIdx.x, qt = blockIdx.y, b = blockIdx.z;
    const int t = threadIdx.x;

    {
        const int r = t >> 3, c = (t & 7) * 16;
        const __half2* qh = (const __half2*)(eq + (size_t)(b * 256 + qt * 32 + r) * 128 + c);
        const __half2* kh = (const __half2*)(ek + (size_t)(b * 256 + kt * 32 + r) * 128 + c);
        #pragma unroll
        for (int j = 0; j < 8; ++j) {
            float2 fq = __half22float2(qh[j]);
            float2 fk = __half22float2(kh[j]);
            *(float2*)&qs[r * LDP + c + 2 * j]  = fq;
            *(float2*)&ks_[r * LDP + c + 2 * j] = fk;
        }
    }
    __syncthreads();

    const int lk = (t & 15) * 2;
    const int lq = (t >> 4) * 2;

    float a00 = 0.f, a01 = 0.f, a10 = 0.f, a11 = 0.f;
    float wsum = 0.f;

    #pragma unroll 4
    for (int h = 0; h < 128; h += 4) {
        float4 w4 = *(const float4*)&wv[h];
        wsum += (w4.x + w4.y) + (w4.z + w4.w);
        float4 qa = *(const float4*)&qs[lq * LDP + h];
        float4 qb = *(const float4*)&qs[(lq + 1) * LDP + h];
        float4 ka = *(const float4*)&ks_[lk * LDP + h];
        float4 kb = *(const float4*)&ks_[(lk + 1) * LDP + h];
        const float wj[4]  = {w4.x, w4.y, w4.z, w4.w};
        const float qaj[4] = {qa.x, qa.y, qa.z, qa.w};
        const float qbj[4] = {qb.x, qb.y, qb.z, qb.w};
        const float kaj[4] = {ka.x, ka.y, ka.z, ka.w};
        const float kbj[4] = {kb.x, kb.y, kb.z, kb.w};
        #pragma unroll
        for (int j = 0; j < 4; ++j) {
            float r00 = __builtin_amdgcn_rcpf(fmaf(qaj[j], kaj[j], 1.0f));
            float r01 = __builtin_amdgcn_rcpf(fmaf(qaj[j], kbj[j], 1.0f));
            float r10 = __builtin_amdgcn_rcpf(fmaf(qbj[j], kaj[j], 1.0f));
            float r11 = __builtin_amdgcn_rcpf(fmaf(qbj[j], kbj[j], 1.0f));
            a00 = fmaf(wj[j], r00, a00);
            a01 = fmaf(wj[j], r01, a01);
            a10 = fmaf(wj[j], r10, a10);
            a11 = fmaf(wj[j], r11, a11);
        }
    }

    const float wsl = fmaf(wsum, LOG2E, -0.5f);
    const float M2L = -2.0f * LOG2E;
    float p00 = __builtin_amdgcn_exp2f(fmaf(M2L, a00, wsl));
    float p01 = __builtin_amdgcn_exp2f(fmaf(M2L, a01, wsl));
    float p10 = __builtin_amdgcn_exp2f(fmaf(M2L, a10, wsl));
    float p11 = __builtin_amdgcn_exp2f(fmaf(M2L, a11, wsl));

    const int q = qt * 32 + lq;
    const int k = kt * 32 + lk;
    *(__half2*)&P[((size_t)(b * 256 + q)) * 256 + k]     = __floats2half2_rn(p00, p01);
    *(__half2*)&P[((size_t)(b * 256 + q + 1)) * 256 + k] = __floats2half2_rn(p10, p11);

    float sa = p00 + p10;
    float sb = p01 + p11;
    sa += __shfl_xor(sa, 16, 64);
    sa += __shfl_xor(sa, 32, 64);
    sb += __shfl_xor(sb, 16, 64);
    sb += __shfl_xor(sb, 32, 64);
    const int wid = t >> 6;
    if ((t & 63) < 16) {
        part2[wid][lk]     = sa;
        part2[wid][lk + 1] = sb;
    }
    __syncthreads();
    if (t < 32) {
        float z = part2[0][t] + part2[1][t] + part2[2][t] + part2[3][t];
        Zpart[(size_t)b * 2048 + qt * 256 + kt * 32 + t] = z;
    }
}

// Kernel 3: pv (verbatim R17).
__global__ __launch_bounds__(256) void pv_kernel(
    const __half* __restrict__ P, const float* __restrict__ Zpart,
    const float* __restrict__ values, float* __restrict__ out)
{
    __shared__ float ps[4 * 260];
    __shared__ float red[4 * 512];
    const int b  = blockIdx.x >> 6;
    const int q0 = (blockIdx.x & 63) * 4;
    const int t  = threadIdx.x;

    {
        const int q = t >> 6;
        const int k = (t & 63) * 4;
        const float* zb = Zpart + (size_t)b * 2048 + k;
        float4 z = make_float4(0.f, 0.f, 0.f, 0.f);
        #pragma unroll
        for (int qt = 0; qt < 8; ++qt) {
            float4 a = *(const float4*)(zb + qt * 256);
            z.x += a.x; z.y += a.y; z.z += a.z; z.w += a.w;
        }
        const __half* prow = P + ((size_t)(b * 256 + q0 + q)) * 256 + k;
        float2 s0 = __half22float2(*(const __half2*)(prow));
        float2 s1 = __half22float2(*(const __half2*)(prow + 2));
        float4 r;
        r.x = s0.x * __builtin_amdgcn_rcpf(z.x);
        r.y = s0.y * __builtin_amdgcn_rcpf(z.y);
        r.z = s1.x * __builtin_amdgcn_rcpf(z.z);
        r.w = s1.y * __builtin_amdgcn_rcpf(z.w);
        *(float4*)&ps[q * 260 + k] = r;
    }
    __syncthreads();

    const int wid  = t >> 6;
    const int lane = t & 63;
    const float* vb = values + (size_t)b * 256 * 128 + lane * 2;

    float ax[4] = {0.f, 0.f, 0.f, 0.f};
    float ay[4] = {0.f, 0.f, 0.f, 0.f};

    for (int kk4 = wid * 16; kk4 < wid * 16 + 16; ++kk4) {
        float4 p0 = *(const float4*)&ps[0 * 260 + kk4 * 4];
        float4 p1 = *(const float4*)&ps[1 * 260 + kk4 * 4];
        float4 p2 = *(const float4*)&ps[2 * 260 + kk4 * 4];
        float4 p3 = *(const float4*)&ps[3 * 260 + kk4 * 4];
        #pragma unroll
        for (int u = 0; u < 4; ++u) {
            int kk = kk4 * 4 + u;
            float2 v = *(const float2*)(vb + (size_t)kk * 128);
            float f0 = (&p0.x)[u], f1 = (&p1.x)[u], f2 = (&p2.x)[u], f3 = (&p3.x)[u];
            ax[0] = fmaf(f0, v.x, ax[0]); ay[0] = fmaf(f0, v.y, ay[0]);
            ax[1] = fmaf(f1, v.x, ax[1]); ay[1] = fmaf(f1, v.y, ay[1]);
            ax[2] = fmaf(f2, v.x, ax[2]); ay[2] = fmaf(f2, v.y, ay[2]);
            ax[3] = fmaf(f3, v.x, ax[3]); ay[3] = fmaf(f3, v.y, ay[3]);
        }
    }

    #pragma unroll
    for (int q = 0; q < 4; ++q)
        *(float2*)&red[wid * 512 + q * 128 + lane * 2] = make_float2(ax[q], ay[q]);
    __syncthreads();

    {
        const int j = t * 2;
        float2 s = make_float2(0.f, 0.f);
        #pragma unroll
        for (int w = 0; w < 4; ++w) {
            float2 r = *(const float2*)&red[w * 512 + j];
            s.x += r.x; s.y += r.y;
        }
        const int q = j >> 7, d = j & 127;
        *(float2*)&out[((size_t)(b * 256 + q0 + q)) * 128 + d] = s;
    }
}

// ---------------------------------------------------------------------------
extern "C" void kernel_launch(void* const* d_in, const int* in_sizes, int n_in,
                              void* d_out, int out_size, void* d_ws, size_t ws_size,
                              hipStream_t stream)
{
    const float* queries = (const float*)d_in[0];  // (8,256,128)
    const float* keys    = (const float*)d_in[1];  // (8,256,128)
    const float* values  = (const float*)d_in[2];  // (8,256,128)
    const float* Wq      = (const float*)d_in[3];  // (128,128)
    const float* Wk      = (const float*)d_in[4];  // (128,128)
    const float* wv      = (const float*)d_in[5];  // (128,)
    float* out = (float*)d_out;                    // (8,256,128)

    float* ws = (float*)d_ws;
    __half* eqb  = (__half*)ws;              // 262144 halves (512KB)
    __half* ekb  = (__half*)(ws + 131072);   // 262144 halves (512KB)
    __half* P    = (__half*)(ws + 262144);   // 524288 halves (1MB)
    float* Zpart = ws + 524288;              // 16384 floats

    proj_kernel<<<512, 256, 0, stream>>>(queries, keys, Wq, Wk, eqb, ekb);
    scoreP_kernel<<<dim3(8, 8, 8), 256, 0, stream>>>(eqb, ekb, wv, P, Zpart);
    pv_kernel<<<512, 256, 0, stream>>>(P, Zpart, values, out);
}

// Round 21
// 30.997 us; speedup vs baseline: 1.3912x; 1.0104x over previous
//
#include <hip/hip_runtime.h>
#include <hip/hip_fp16.h>

#define LOG2E    1.4426950408889634f
#define TWOLOG2E 2.8853900817779268f

// ---------------------------------------------------------------------------
// 3-launch pipeline, fp16 intermediates (R20 = 31.3us best).
// scoreP v2: LDS holds fp16 (was fp32-converted-at-stage).  Each
// ds_read_b128 now delivers 8 h-values -> 64 reads/wave (was 128), halving
// the LDS-pipe time that bounds scoreP (5.1us -> ~2.6us/CU); cvt moves to
// the inner loop (+1k cyc VALU/wave, below the 3.4us trans floor).
// Math identical after conversion -> same absmax as R20.
//   K1 proj   -> eq = fp16(exp(2*q@Wq^T)), ek likewise    (R20 scalar-pipe)
//   K2 scoreP -> P = fp16(exp2(score*log2e - 0.5)) + fp32 column partials
//   K3 pv     -> out = (P/Z) @ V                           (R17 verbatim)
// ---------------------------------------------------------------------------

// Kernel 1: projections -> fp16 exponentials (verbatim R20).
__global__ __launch_bounds__(256) void proj_kernel(
    const float* __restrict__ queries, const float* __restrict__ keys,
    const float* __restrict__ Wq, const float* __restrict__ Wk,
    __half* __restrict__ eq, __half* __restrict__ ek)
{
    const int isK = blockIdx.x >= 256;
    const int rowBase = (blockIdx.x & 255) * 8;
    const float* __restrict__ x = isK ? keys : queries;
    const float* __restrict__ W = isK ? Wk : Wq;
    __half* __restrict__ op = isK ? ek : eq;
    const int t = threadIdx.x;

    const int h   = t & 127;
    const int rhu = __builtin_amdgcn_readfirstlane(t >> 7);  // wave-uniform
    const float4* wrow = (const float4*)(W + (size_t)h * 128);
    const float4* xr0 = (const float4*)(x + (size_t)(rowBase + rhu * 4 + 0) * 128);
    const float4* xr1 = (const float4*)(x + (size_t)(rowBase + rhu * 4 + 1) * 128);
    const float4* xr2 = (const float4*)(x + (size_t)(rowBase + rhu * 4 + 2) * 128);
    const float4* xr3 = (const float4*)(x + (size_t)(rowBase + rhu * 4 + 3) * 128);

    float acc[4] = {0.f, 0.f, 0.f, 0.f};

    #pragma unroll 4
    for (int d4 = 0; d4 < 32; ++d4) {
        float4 w  = wrow[d4];            // per-lane row stream (L1/L2)
        float4 x0 = xr0[d4];             // wave-uniform -> s_load_dwordx4
        float4 x1 = xr1[d4];
        float4 x2 = xr2[d4];
        float4 x3 = xr3[d4];
        acc[0] = fmaf(x0.x, w.x, acc[0]); acc[0] = fmaf(x0.y, w.y, acc[0]);
        acc[0] = fmaf(x0.z, w.z, acc[0]); acc[0] = fmaf(x0.w, w.w, acc[0]);
        acc[1] = fmaf(x1.x, w.x, acc[1]); acc[1] = fmaf(x1.y, w.y, acc[1]);
        acc[1] = fmaf(x1.z, w.z, acc[1]); acc[1] = fmaf(x1.w, w.w, acc[1]);
        acc[2] = fmaf(x2.x, w.x, acc[2]); acc[2] = fmaf(x2.y, w.y, acc[2]);
        acc[2] = fmaf(x2.z, w.z, acc[2]); acc[2] = fmaf(x2.w, w.w, acc[2]);
        acc[3] = fmaf(x3.x, w.x, acc[3]); acc[3] = fmaf(x3.y, w.y, acc[3]);
        acc[3] = fmaf(x3.z, w.z, acc[3]); acc[3] = fmaf(x3.w, w.w, acc[3]);
    }
    #pragma unroll
    for (int r = 0; r < 4; ++r)
        op[(size_t)(rowBase + rhu * 4 + r) * 128 + h] =
            __float2half(__builtin_amdgcn_exp2f(acc[r] * TWOLOG2E));
}

// Kernel 2: scoreP with fp16 LDS.  LDP_H = 132 halves -> 2-way conflicts only.
#define LDP_H 132

__global__ __launch_bounds__(256) void scoreP_kernel(
    const __half* __restrict__ eq, const __half* __restrict__ ek,
    const float* __restrict__ wv, __half* __restrict__ P,
    float* __restrict__ Zpart)
{
    __shared__ __half qs[32 * LDP_H];
    __shared__ __half ks_[32 * LDP_H];
    __shared__ float part2[4][32];

    const int kt = blockIdx.x, qt = blockIdx.y, b = blockIdx.z;
    const int t = threadIdx.x;

    // stage fp16 -> fp16 LDS (pure copy, 2x uint4 per array per thread)
    {
        const int r = t >> 3, c = (t & 7) * 16;
        const uint4* qg = (const uint4*)(eq + (size_t)(b * 256 + qt * 32 + r) * 128 + c);
        const uint4* kg = (const uint4*)(ek + (size_t)(b * 256 + kt * 32 + r) * 128 + c);
        *(uint4*)&qs[r * LDP_H + c]      = qg[0];
        *(uint4*)&qs[r * LDP_H + c + 8]  = qg[1];
        *(uint4*)&ks_[r * LDP_H + c]     = kg[0];
        *(uint4*)&ks_[r * LDP_H + c + 8] = kg[1];
    }
    __syncthreads();

    const int lk = (t & 15) * 2;
    const int lq = (t >> 4) * 2;

    float a00 = 0.f, a01 = 0.f, a10 = 0.f, a11 = 0.f;
    float wsum = 0.f;

    #pragma unroll 4
    for (int h = 0; h < 128; h += 8) {
        float4 w4a = *(const float4*)&wv[h];         // uniform -> s_load
        float4 w4b = *(const float4*)&wv[h + 4];
        wsum += (w4a.x + w4a.y) + (w4a.z + w4a.w)
              + (w4b.x + w4b.y) + (w4b.z + w4b.w);
        const float wj[8] = {w4a.x, w4a.y, w4a.z, w4a.w,
                             w4b.x, w4b.y, w4b.z, w4b.w};

        uint4 qa8 = *(const uint4*)&qs[lq * LDP_H + h];          // 8 halves
        uint4 qb8 = *(const uint4*)&qs[(lq + 1) * LDP_H + h];
        uint4 ka8 = *(const uint4*)&ks_[lk * LDP_H + h];
        uint4 kb8 = *(const uint4*)&ks_[(lk + 1) * LDP_H + h];

        const unsigned* qaw = (const unsigned*)&qa8;
        const unsigned* qbw = (const unsigned*)&qb8;
        const unsigned* kaw = (const unsigned*)&ka8;
        const unsigned* kbw = (const unsigned*)&kb8;

        #pragma unroll
        for (int wd = 0; wd < 4; ++wd) {             // 2 h per word
            float2 qa = __half22float2(*(const __half2*)&qaw[wd]);
            float2 qb = __half22float2(*(const __half2*)&qbw[wd]);
            float2 ka = __half22float2(*(const __half2*)&kaw[wd]);
            float2 kb = __half22float2(*(const __half2*)&kbw[wd]);
            const float w0 = wj[wd * 2], w1 = wj[wd * 2 + 1];

            float r00 = __builtin_amdgcn_rcpf(fmaf(qa.x, ka.x, 1.0f));
            float r01 = __builtin_amdgcn_rcpf(fmaf(qa.x, kb.x, 1.0f));
            float r10 = __builtin_amdgcn_rcpf(fmaf(qb.x, ka.x, 1.0f));
            float r11 = __builtin_amdgcn_rcpf(fmaf(qb.x, kb.x, 1.0f));
            a00 = fmaf(w0, r00, a00);
            a01 = fmaf(w0, r01, a01);
            a10 = fmaf(w0, r10, a10);
            a11 = fmaf(w0, r11, a11);

            r00 = __builtin_amdgcn_rcpf(fmaf(qa.y, ka.y, 1.0f));
            r01 = __builtin_amdgcn_rcpf(fmaf(qa.y, kb.y, 1.0f));
            r10 = __builtin_amdgcn_rcpf(fmaf(qb.y, ka.y, 1.0f));
            r11 = __builtin_amdgcn_rcpf(fmaf(qb.y, kb.y, 1.0f));
            a00 = fmaf(w1, r00, a00);
            a01 = fmaf(w1, r01, a01);
            a10 = fmaf(w1, r10, a10);
            a11 = fmaf(w1, r11, a11);
        }
    }

    const float wsl = fmaf(wsum, LOG2E, -0.5f);
    const float M2L = -2.0f * LOG2E;
    float p00 = __builtin_amdgcn_exp2f(fmaf(M2L, a00, wsl));
    float p01 = __builtin_amdgcn_exp2f(fmaf(M2L, a01, wsl));
    float p10 = __builtin_amdgcn_exp2f(fmaf(M2L, a10, wsl));
    float p11 = __builtin_amdgcn_exp2f(fmaf(M2L, a11, wsl));

    const int q = qt * 32 + lq;
    const int k = kt * 32 + lk;
    *(__half2*)&P[((size_t)(b * 256 + q)) * 256 + k]     = __floats2half2_rn(p00, p01);
    *(__half2*)&P[((size_t)(b * 256 + q + 1)) * 256 + k] = __floats2half2_rn(p10, p11);

    float sa = p00 + p10;
    float sb = p01 + p11;
    sa += __shfl_xor(sa, 16, 64);
    sa += __shfl_xor(sa, 32, 64);
    sb += __shfl_xor(sb, 16, 64);
    sb += __shfl_xor(sb, 32, 64);
    const int wid = t >> 6;
    if ((t & 63) < 16) {
        part2[wid][lk]     = sa;
        part2[wid][lk + 1] = sb;
    }
    __syncthreads();
    if (t < 32) {
        float z = part2[0][t] + part2[1][t] + part2[2][t] + part2[3][t];
        Zpart[(size_t)b * 2048 + qt * 256 + kt * 32 + t] = z;
    }
}

// Kernel 3: pv (verbatim R17/R20).
__global__ __launch_bounds__(256) void pv_kernel(
    const __half* __restrict__ P, const float* __restrict__ Zpart,
    const float* __restrict__ values, float* __restrict__ out)
{
    __shared__ float ps[4 * 260];
    __shared__ float red[4 * 512];
    const int b  = blockIdx.x >> 6;
    const int q0 = (blockIdx.x & 63) * 4;
    const int t  = threadIdx.x;

    {
        const int q = t >> 6;
        const int k = (t & 63) * 4;
        const float* zb = Zpart + (size_t)b * 2048 + k;
        float4 z = make_float4(0.f, 0.f, 0.f, 0.f);
        #pragma unroll
        for (int qt = 0; qt < 8; ++qt) {
            float4 a = *(const float4*)(zb + qt * 256);
            z.x += a.x; z.y += a.y; z.z += a.z; z.w += a.w;
        }
        const __half* prow = P + ((size_t)(b * 256 + q0 + q)) * 256 + k;
        float2 s0 = __half22float2(*(const __half2*)(prow));
        float2 s1 = __half22float2(*(const __half2*)(prow + 2));
        float4 r;
        r.x = s0.x * __builtin_amdgcn_rcpf(z.x);
        r.y = s0.y * __builtin_amdgcn_rcpf(z.y);
        r.z = s1.x * __builtin_amdgcn_rcpf(z.z);
        r.w = s1.y * __builtin_amdgcn_rcpf(z.w);
        *(float4*)&ps[q * 260 + k] = r;
    }
    __syncthreads();

    const int wid  = t >> 6;
    const int lane = t & 63;
    const float* vb = values + (size_t)b * 256 * 128 + lane * 2;

    float ax[4] = {0.f, 0.f, 0.f, 0.f};
    float ay[4] = {0.f, 0.f, 0.f, 0.f};

    for (int kk4 = wid * 16; kk4 < wid * 16 + 16; ++kk4) {
        float4 p0 = *(const float4*)&ps[0 * 260 + kk4 * 4];
        float4 p1 = *(const float4*)&ps[1 * 260 + kk4 * 4];
        float4 p2 = *(const float4*)&ps[2 * 260 + kk4 * 4];
        float4 p3 = *(const float4*)&ps[3 * 260 + kk4 * 4];
        #pragma unroll
        for (int u = 0; u < 4; ++u) {
            int kk = kk4 * 4 + u;
            float2 v = *(const float2*)(vb + (size_t)kk * 128);
            float f0 = (&p0.x)[u], f1 = (&p1.x)[u], f2 = (&p2.x)[u], f3 = (&p3.x)[u];
            ax[0] = fmaf(f0, v.x, ax[0]); ay[0] = fmaf(f0, v.y, ay[0]);
            ax[1] = fmaf(f1, v.x, ax[1]); ay[1] = fmaf(f1, v.y, ay[1]);
            ax[2] = fmaf(f2, v.x, ax[2]); ay[2] = fmaf(f2, v.y, ay[2]);
            ax[3] = fmaf(f3, v.x, ax[3]); ay[3] = fmaf(f3, v.y, ay[3]);
        }
    }

    #pragma unroll
    for (int q = 0; q < 4; ++q)
        *(float2*)&red[wid * 512 + q * 128 + lane * 2] = make_float2(ax[q], ay[q]);
    __syncthreads();

    {
        const int j = t * 2;
        float2 s = make_float2(0.f, 0.f);
        #pragma unroll
        for (int w = 0; w < 4; ++w) {
            float2 r = *(const float2*)&red[w * 512 + j];
            s.x += r.x; s.y += r.y;
        }
        const int q = j >> 7, d = j & 127;
        *(float2*)&out[((size_t)(b * 256 + q0 + q)) * 128 + d] = s;
    }
}

// ---------------------------------------------------------------------------
extern "C" void kernel_launch(void* const* d_in, const int* in_sizes, int n_in,
                              void* d_out, int out_size, void* d_ws, size_t ws_size,
                              hipStream_t stream)
{
    const float* queries = (const float*)d_in[0];  // (8,256,128)
    const float* keys    = (const float*)d_in[1];  // (8,256,128)
    const float* values  = (const float*)d_in[2];  // (8,256,128)
    const float* Wq      = (const float*)d_in[3];  // (128,128)
    const float* Wk      = (const float*)d_in[4];  // (128,128)
    const float* wv      = (const float*)d_in[5];  // (128,)
    float* out = (float*)d_out;                    // (8,256,128)

    float* ws = (float*)d_ws;
    __half* eqb  = (__half*)ws;              // 262144 halves (512KB)
    __half* ekb  = (__half*)(ws + 131072);   // 262144 halves (512KB)
    __half* P    = (__half*)(ws + 262144);   // 524288 halves (1MB)
    float* Zpart = ws + 524288;              // 16384 floats

    proj_kernel<<<512, 256, 0, stream>>>(queries, keys, Wq, Wk, eqb, ekb);
    scoreP_kernel<<<dim3(8, 8, 8), 256, 0, stream>>>(eqb, ekb, wv, P, Zpart);
    pv_kernel<<<512, 256, 0, stream>>>(P, Zpart, values, out);
}